// Round 3
// baseline (991.366 us; speedup 1.0000x reference)
//
#include <hip/hip_runtime.h>
#include <hip/hip_bf16.h>

// Problem constants
#define NB   64      // batch N
#define TT   12      // T
#define VV   256     // V (vertices)
#define CIN  64
#define COUT 64
#define VSQ  65536   // V*V

// ---------------------------------------------------------------------------
// K1: y[n,o,t,v] = sum_c x[n,c,t,v] * conv_w[o,c] + conv_b[o]
// block = (n*T + t), 256 threads (thread = v). x column in VGPRs, weights
// via wave-uniform s_loads. Output -> d_ws (so K3 reads a never-written
// buffer -> compiler emits scalar loads there).
// ---------------------------------------------------------------------------
__global__ __launch_bounds__(256) void k1_conv(
    const float* __restrict__ x, const float* __restrict__ w,
    const float* __restrict__ b, float* __restrict__ y)
{
    const int nt = blockIdx.x;
    const int n  = nt / TT;
    const int t  = nt % TT;
    const int v  = threadIdx.x;

    const float* xp = x + ((long)n * CIN * TT + t) * VV + v;
    float xv[CIN];
    #pragma unroll 8
    for (int c = 0; c < CIN; ++c)
        xv[c] = xp[(long)c * TT * VV];          // coalesced

    float* yp = y + ((long)n * COUT * TT + t) * VV + v;

    for (int o0 = 0; o0 < COUT; o0 += 16) {
        float acc[16];
        #pragma unroll
        for (int i = 0; i < 16; ++i) acc[i] = b[o0 + i];
        #pragma unroll 8
        for (int c = 0; c < CIN; ++c) {
            const float xc = xv[c];
            #pragma unroll
            for (int i = 0; i < 16; ++i)
                acc[i] += w[(o0 + i) * CIN + c] * xc;   // uniform -> s_load
        }
        #pragma unroll
        for (int i = 0; i < 16; ++i)
            yp[(long)(o0 + i) * TT * VV] = acc[i];
    }
}

// ---------------------------------------------------------------------------
// K2: Aw[n,c,v,w] = relu(W3 relu(W2 relu(W1 feats + b1) + b2) + b3) * mask
// One thread per (n,v,w). Weight rows batch into s_load_dwordx16; h1/h2 in
// VGPRs. ~VALU-bound (143 us floor) overlapped with 1.07 GB write.
// ---------------------------------------------------------------------------
__global__ __launch_bounds__(256) void k2_mlp(
    const float* __restrict__ A,
    const float* __restrict__ w1, const float* __restrict__ b1,
    const float* __restrict__ w2, const float* __restrict__ b2,
    const float* __restrict__ w3, const float* __restrict__ b3,
    float* __restrict__ Aw)
{
    const long idx = (long)blockIdx.x * 256 + threadIdx.x;  // n*VSQ + v*V + w
    const int  n   = (int)(idx >> 16);
    const int  rem = (int)(idx & (VSQ - 1));

    const float* ap = A + ((long)n * 8 << 16) + rem;
    float f[7];
    #pragma unroll
    for (int c = 0; c < 7; ++c) f[c] = ap[(long)c << 16];
    const float m = ap[(long)7 << 16];

    float h1[16];
    #pragma unroll
    for (int o = 0; o < 16; ++o) {
        float acc = b1[o];
        #pragma unroll
        for (int k = 0; k < 7; ++k) acc += w1[o * 7 + k] * f[k];
        h1[o] = fmaxf(acc, 0.f);
    }

    float h2[32];
    #pragma unroll
    for (int o = 0; o < 32; ++o) {
        float acc = b2[o];
        #pragma unroll
        for (int k = 0; k < 16; ++k) acc += w2[o * 16 + k] * h1[k];
        h2[o] = fmaxf(acc, 0.f);
    }

    float* op = Aw + ((long)n * COUT << 16) + rem;
    #pragma unroll 8
    for (int o = 0; o < COUT; ++o) {
        float acc = b3[o];
        #pragma unroll
        for (int k = 0; k < 32; ++k) acc += w3[o * 32 + k] * h2[k];
        op[(long)o << 16] = fmaxf(acc, 0.f) * m;
    }
}

// ---------------------------------------------------------------------------
// K3: out[n,c,t,w] = sum_v y[n,c,t,v] * Aw[n,c,v,w]
// block = (n*COUT + c), 256 threads (thread = w). y lives in d_ws and is
// NEVER written here -> uniform indices compile to s_load_dwordx4; the FMAs
// consume x' directly as SGPR operands (v_fmac v, s, v). LDS-free, the only
// vector traffic is the coalesced streaming Aw read (HBM-bound, ~170 us).
// ---------------------------------------------------------------------------
__global__ __launch_bounds__(256) void k3_einsum(
    const float* __restrict__ Aw, const float* __restrict__ y,
    float* __restrict__ out)
{
    const int nc = blockIdx.x;          // n*64 + c
    const int w  = threadIdx.x;

    const float* __restrict__ yp  = y + (long)nc * TT * VV;   // uniform base
    const float* __restrict__ awp = Aw + ((long)nc << 16) + w;

    float acc[TT];
    #pragma unroll
    for (int t = 0; t < TT; ++t) acc[t] = 0.f;

    for (int v0 = 0; v0 < VV; v0 += 4) {
        const float aw0 = awp[(long)(v0 + 0) * VV];   // coalesced 256B/instr
        const float aw1 = awp[(long)(v0 + 1) * VV];
        const float aw2 = awp[(long)(v0 + 2) * VV];
        const float aw3 = awp[(long)(v0 + 3) * VV];
        #pragma unroll
        for (int t = 0; t < TT; ++t) {
            const float4 xt = *reinterpret_cast<const float4*>(yp + t * VV + v0);
            acc[t] += xt.x * aw0 + xt.y * aw1 + xt.z * aw2 + xt.w * aw3;
        }
    }

    float* op = out + (long)nc * TT * VV + w;
    #pragma unroll
    for (int t = 0; t < TT; ++t)
        op[t * VV] = acc[t];
}

// Fallback (ws too small): in-place over the out region, LDS-staged reads.
__global__ __launch_bounds__(256) void k3_einsum_inplace(
    const float* __restrict__ Aw, float* y)
{
    const int nc = blockIdx.x;
    const int w  = threadIdx.x;

    __shared__ float ys[TT][VV];
    const float* yp = y + (long)nc * TT * VV;
    #pragma unroll
    for (int t = 0; t < TT; ++t) ys[t][w] = yp[t * VV + w];
    __syncthreads();

    const float* awp = Aw + ((long)nc << 16) + w;
    float acc[TT];
    #pragma unroll
    for (int t = 0; t < TT; ++t) acc[t] = 0.f;
    for (int v = 0; v < VV; ++v) {
        const float aw = awp[(long)v * VV];
        #pragma unroll
        for (int t = 0; t < TT; ++t) acc[t] += ys[t][v] * aw;
    }
    float* op = y + (long)nc * TT * VV + w;
    #pragma unroll
    for (int t = 0; t < TT; ++t) op[t * VV] = acc[t];
}

// ---------------------------------------------------------------------------
extern "C" void kernel_launch(void* const* d_in, const int* in_sizes, int n_in,
                              void* d_out, int out_size, void* d_ws, size_t ws_size,
                              hipStream_t stream)
{
    const float* x      = (const float*)d_in[0];
    const float* A      = (const float*)d_in[1];
    const float* conv_w = (const float*)d_in[2];
    const float* conv_b = (const float*)d_in[3];
    const float* w1     = (const float*)d_in[4];
    const float* b1     = (const float*)d_in[5];
    const float* w2     = (const float*)d_in[6];
    const float* b2     = (const float*)d_in[7];
    const float* w3     = (const float*)d_in[8];
    const float* b3     = (const float*)d_in[9];

    float* out   = (float*)d_out;                                   // (64,64,12,256)
    float* Aw    = (float*)d_out + (long)NB * COUT * TT * VV;       // (64,64,256,256)
    const size_t y_bytes = (size_t)NB * COUT * TT * VV * sizeof(float);

    // K2: MLP + mask -> Aw (independent of K1; launch first for overlap slack)
    k2_mlp<<<(NB * VSQ) / 256, 256, 0, stream>>>(A, w1, b1, w2, b2, w3, b3, Aw);

    if (ws_size >= y_bytes) {
        float* y = (float*)d_ws;
        k1_conv<<<NB * TT, 256, 0, stream>>>(x, conv_w, conv_b, y);
        k3_einsum<<<NB * COUT, 256, 0, stream>>>(Aw, y, out);
    } else {
        k1_conv<<<NB * TT, 256, 0, stream>>>(x, conv_w, conv_b, out);
        k3_einsum_inplace<<<NB * COUT, 256, 0, stream>>>(Aw, out);
    }
}

// Round 4
// 717.660 us; speedup vs baseline: 1.3814x; 1.3814x over previous
//
#include <hip/hip_runtime.h>
#include <hip/hip_bf16.h>

// Problem constants
#define NB   64      // batch N
#define TT   12      // T
#define VV   256     // V (vertices)
#define CIN  64
#define COUT 64
#define VSQ  65536   // V*V

// ---------------------------------------------------------------------------
// K1: y[n,o,t,v] = sum_c x[n,c,t,v] * conv_w[o,c] + conv_b[o]
// block = (n*T + t), 256 threads (thread = v). x column in VGPRs, weights
// via wave-uniform loads. ~25 us, not on the critical path.
// ---------------------------------------------------------------------------
__global__ __launch_bounds__(256) void k1_conv(
    const float* __restrict__ x, const float* __restrict__ w,
    const float* __restrict__ b, float* __restrict__ y)
{
    const int nt = blockIdx.x;
    const int n  = nt / TT;
    const int t  = nt % TT;
    const int v  = threadIdx.x;

    const float* xp = x + ((long)n * CIN * TT + t) * VV + v;
    float xv[CIN];
    #pragma unroll 8
    for (int c = 0; c < CIN; ++c)
        xv[c] = xp[(long)c * TT * VV];          // coalesced

    float* yp = y + ((long)n * COUT * TT + t) * VV + v;

    for (int o0 = 0; o0 < COUT; o0 += 16) {
        float acc[16];
        #pragma unroll
        for (int i = 0; i < 16; ++i) acc[i] = b[o0 + i];
        #pragma unroll 8
        for (int c = 0; c < CIN; ++c) {
            const float xc = xv[c];
            #pragma unroll
            for (int i = 0; i < 16; ++i)
                acc[i] += w[(o0 + i) * CIN + c] * xc;
        }
        #pragma unroll
        for (int i = 0; i < 16; ++i)
            yp[(long)(o0 + i) * TT * VV] = acc[i];
    }
}

// ---------------------------------------------------------------------------
// K2: Aw[n,c,v,w] = relu(W3 relu(W2 relu(W1 feats + b1) + b2) + b3) * mask
// Weights staged in LDS, consumed as broadcast ds_read_b128 (4 wts/instr).
// Each thread computes 2 adjacent positions (float2 loads/stores) so every
// weight read feeds 2 FMAs. Block covers 512 consecutive (v,w) positions.
// ---------------------------------------------------------------------------
__global__ __launch_bounds__(256) void k2_mlp(
    const float* __restrict__ A,
    const float* __restrict__ w1, const float* __restrict__ b1,
    const float* __restrict__ w2, const float* __restrict__ b2,
    const float* __restrict__ w3, const float* __restrict__ b3,
    float* __restrict__ Aw)
{
    __shared__ float s1[16 * 8];      // w1 padded 7->8 per row
    __shared__ float sb1[16];
    __shared__ float s2[32 * 16];
    __shared__ float sb2[32];
    __shared__ float s3[64 * 32];
    __shared__ float sb3[64];

    const int tid = threadIdx.x;

    // cooperative weight staging
    if (tid < 128) s1[tid] = ((tid & 7) < 7) ? w1[(tid >> 3) * 7 + (tid & 7)] : 0.f;
    else if (tid < 144) sb1[tid - 128] = b1[tid - 128];
    else if (tid < 176) sb2[tid - 144] = b2[tid - 144];
    else if (tid < 240) sb3[tid - 176] = b3[tid - 176];
    for (int i = tid; i < 512;  i += 256) s2[i] = w2[i];
    for (int i = tid; i < 2048; i += 256) s3[i] = w3[i];
    __syncthreads();

    const long base = (long)blockIdx.x * 512;      // grid = NB*VSQ/512
    const int  n    = (int)(base >> 16);
    const int  rem  = ((int)(base & (VSQ - 1))) + 2 * tid;

    const float* ap = A + ((long)n * 8 << 16) + rem;
    float fa[8], fb[8];
    #pragma unroll
    for (int c = 0; c < 7; ++c) {
        const float2 f2 = *reinterpret_cast<const float2*>(ap + ((long)c << 16));
        fa[c] = f2.x; fb[c] = f2.y;
    }
    fa[7] = 0.f; fb[7] = 0.f;
    const float2 m = *reinterpret_cast<const float2*>(ap + ((long)7 << 16));

    // layer 1: 7 -> 16
    float h1a[16], h1b[16];
    #pragma unroll
    for (int o = 0; o < 16; ++o) {
        float a = sb1[o], bb = a;
        #pragma unroll
        for (int k4 = 0; k4 < 8; k4 += 4) {
            const float4 wv = *reinterpret_cast<const float4*>(&s1[o * 8 + k4]);
            a  += wv.x * fa[k4] + wv.y * fa[k4 + 1] + wv.z * fa[k4 + 2] + wv.w * fa[k4 + 3];
            bb += wv.x * fb[k4] + wv.y * fb[k4 + 1] + wv.z * fb[k4 + 2] + wv.w * fb[k4 + 3];
        }
        h1a[o] = fmaxf(a, 0.f); h1b[o] = fmaxf(bb, 0.f);
    }

    // layer 2: 16 -> 32
    float h2a[32], h2b[32];
    #pragma unroll
    for (int o = 0; o < 32; ++o) {
        float a = sb2[o], bb = a;
        #pragma unroll
        for (int k4 = 0; k4 < 16; k4 += 4) {
            const float4 wv = *reinterpret_cast<const float4*>(&s2[o * 16 + k4]);
            a  += wv.x * h1a[k4] + wv.y * h1a[k4 + 1] + wv.z * h1a[k4 + 2] + wv.w * h1a[k4 + 3];
            bb += wv.x * h1b[k4] + wv.y * h1b[k4 + 1] + wv.z * h1b[k4 + 2] + wv.w * h1b[k4 + 3];
        }
        h2a[o] = fmaxf(a, 0.f); h2b[o] = fmaxf(bb, 0.f);
    }

    // layer 3: 32 -> 64, o-chunks of 8, relu * mask, float2 stores
    float* op = Aw + ((long)n * COUT << 16) + rem;
    for (int o0 = 0; o0 < 64; o0 += 8) {
        float accA[8], accB[8];
        #pragma unroll
        for (int i = 0; i < 8; ++i) { accA[i] = sb3[o0 + i]; accB[i] = accA[i]; }
        #pragma unroll
        for (int k4 = 0; k4 < 32; k4 += 4) {
            #pragma unroll
            for (int i = 0; i < 8; ++i) {
                const float4 wv = *reinterpret_cast<const float4*>(&s3[(o0 + i) * 32 + k4]);
                accA[i] += wv.x * h2a[k4] + wv.y * h2a[k4 + 1] + wv.z * h2a[k4 + 2] + wv.w * h2a[k4 + 3];
                accB[i] += wv.x * h2b[k4] + wv.y * h2b[k4 + 1] + wv.z * h2b[k4 + 2] + wv.w * h2b[k4 + 3];
            }
        }
        #pragma unroll
        for (int i = 0; i < 8; ++i) {
            float2 r;
            r.x = fmaxf(accA[i], 0.f) * m.x;
            r.y = fmaxf(accB[i], 0.f) * m.y;
            *reinterpret_cast<float2*>(op + ((long)(o0 + i) << 16)) = r;
        }
    }
}

// ---------------------------------------------------------------------------
// K3: out[n,c,t,w] = sum_v y[n,c,t,v] * Aw[n,c,v,w]
// block = (n, c-quad): 1024 blocks, 256 threads = 4 c-lanes x 64 w-lanes,
// thread owns 4 w (float4). y tiles (4 x 12 x 256 = 48 KB) staged in LDS;
// per v-step: 12 broadcast ds_reads feed 48 FMAs + one 16B/lane Aw load.
// Works in-place (out may alias y): y is only read during staging, before
// the barrier; all global writes happen after.
// ---------------------------------------------------------------------------
__global__ __launch_bounds__(256) void k3_einsum(
    const float* __restrict__ Aw, const float* __restrict__ y,
    float* __restrict__ out)
{
    __shared__ float ys[4][TT][VV];     // 48 KiB

    const int n   = blockIdx.x >> 4;
    const int c0  = (blockIdx.x & 15) * 4;
    const int tid = threadIdx.x;
    const int cq  = tid >> 6;           // 0..3
    const int w4  = (tid & 63) * 4;     // 0..252

    // stage 4 y tiles: 3072 float4s, 12 per thread, coalesced
    {
        const float* src = y + ((long)(n * COUT + c0) * TT) * VV;
        float* dst = &ys[0][0][0];
        #pragma unroll
        for (int it = 0; it < 12; ++it) {
            const int idx = tid + it * 256;           // float4 index in [0,3072)
            *reinterpret_cast<float4*>(dst + idx * 4) =
                *reinterpret_cast<const float4*>(src + idx * 4);
        }
    }
    __syncthreads();

    const float* awp = Aw + (((long)(n * COUT + c0 + cq)) << 16) + w4;
    float4 acc[TT];
    #pragma unroll
    for (int t = 0; t < TT; ++t) acc[t] = make_float4(0.f, 0.f, 0.f, 0.f);

    #pragma unroll 2
    for (int v = 0; v < VV; ++v) {
        const float4 aw = *reinterpret_cast<const float4*>(awp + (long)v * VV);
        #pragma unroll
        for (int t = 0; t < TT; ++t) {
            const float xs = ys[cq][t][v];            // uniform broadcast
            acc[t].x += xs * aw.x;
            acc[t].y += xs * aw.y;
            acc[t].z += xs * aw.z;
            acc[t].w += xs * aw.w;
        }
    }

    float* op = out + ((long)(n * COUT + c0 + cq) * TT) * VV + w4;
    #pragma unroll
    for (int t = 0; t < TT; ++t)
        *reinterpret_cast<float4*>(op + t * VV) = acc[t];
}

// ---------------------------------------------------------------------------
extern "C" void kernel_launch(void* const* d_in, const int* in_sizes, int n_in,
                              void* d_out, int out_size, void* d_ws, size_t ws_size,
                              hipStream_t stream)
{
    const float* x      = (const float*)d_in[0];
    const float* A      = (const float*)d_in[1];
    const float* conv_w = (const float*)d_in[2];
    const float* conv_b = (const float*)d_in[3];
    const float* w1     = (const float*)d_in[4];
    const float* b1     = (const float*)d_in[5];
    const float* w2     = (const float*)d_in[6];
    const float* b2     = (const float*)d_in[7];
    const float* w3     = (const float*)d_in[8];
    const float* b3     = (const float*)d_in[9];

    float* out = (float*)d_out;                                  // (64,64,12,256)
    float* Aw  = (float*)d_out + (long)NB * COUT * TT * VV;      // (64,64,256,256)
    const size_t y_bytes = (size_t)NB * COUT * TT * VV * sizeof(float);

    float* y = (ws_size >= y_bytes) ? (float*)d_ws : out;        // k3 handles alias

    // K2: MLP + mask -> Aw
    k2_mlp<<<(NB * VSQ) / 512, 256, 0, stream>>>(A, w1, b1, w2, b2, w3, b3, Aw);

    // K1: conv -> y
    k1_conv<<<NB * TT, 256, 0, stream>>>(x, conv_w, conv_b, y);

    // K3: einsum (in-place safe if y == out)
    k3_einsum<<<NB * (COUT / 4), 256, 0, stream>>>(Aw, y, out);
}

// Round 5
// 714.274 us; speedup vs baseline: 1.3879x; 1.0047x over previous
//
#include <hip/hip_runtime.h>
#include <hip/hip_bf16.h>

// Problem constants
#define NB   64      // batch N
#define TT   12      // T
#define VV   256     // V (vertices)
#define CIN  64
#define COUT 64
#define VSQ  65536   // V*V

// ---------------------------------------------------------------------------
// K1: y[n,o,t,v] = sum_c x[n,c,t,v] * conv_w[o,c] + conv_b[o]
// block = (n*T + t), 256 threads (thread = v). x column in VGPRs, weights
// via wave-uniform global loads (s_load + K$; proven ~BW-floor). ~25 us.
// ---------------------------------------------------------------------------
__global__ __launch_bounds__(256) void k1_conv(
    const float* __restrict__ x, const float* __restrict__ w,
    const float* __restrict__ b, float* __restrict__ y)
{
    const int nt = blockIdx.x;
    const int n  = nt / TT;
    const int t  = nt % TT;
    const int v  = threadIdx.x;

    const float* xp = x + ((long)n * CIN * TT + t) * VV + v;
    float xv[CIN];
    #pragma unroll 8
    for (int c = 0; c < CIN; ++c)
        xv[c] = xp[(long)c * TT * VV];          // coalesced

    float* yp = y + ((long)n * COUT * TT + t) * VV + v;

    for (int o0 = 0; o0 < COUT; o0 += 16) {
        float acc[16];
        #pragma unroll
        for (int i = 0; i < 16; ++i) acc[i] = b[o0 + i];
        #pragma unroll 8
        for (int c = 0; c < CIN; ++c) {
            const float xc = xv[c];
            #pragma unroll
            for (int i = 0; i < 16; ++i)
                acc[i] += w[(o0 + i) * CIN + c] * xc;   // uniform -> s_load
        }
        #pragma unroll
        for (int i = 0; i < 16; ++i)
            yp[(long)(o0 + i) * TT * VV] = acc[i];
    }
}

// ---------------------------------------------------------------------------
// K2: Aw[n,c,v,w] = relu(W3 relu(W2 relu(W1 feats + b1) + b2) + b3) * mask
// K1's proven idiom: weights read from GLOBAL with wave-uniform indices
// (-> s_load + K$, scalar pipe, free) in o-chunks of 16 / live window <=128
// floats. Each thread computes 2 adjacent positions (float2 I/O) so every
// weight feeds 2 FMAs. No LDS anywhere.
// ---------------------------------------------------------------------------
__global__ __launch_bounds__(256) void k2_mlp(
    const float* __restrict__ A,
    const float* __restrict__ w1, const float* __restrict__ b1,
    const float* __restrict__ w2, const float* __restrict__ b2,
    const float* __restrict__ w3, const float* __restrict__ b3,
    float* __restrict__ Aw)
{
    const int  tid  = threadIdx.x;
    const long base = (long)blockIdx.x * 512;      // grid = NB*VSQ/512
    const int  n    = (int)(base >> 16);
    const int  rem  = ((int)(base & (VSQ - 1))) + 2 * tid;

    const float* ap = A + ((long)n * 8 << 16) + rem;
    float fa[7], fb[7];
    #pragma unroll
    for (int c = 0; c < 7; ++c) {
        const float2 f2 = *reinterpret_cast<const float2*>(ap + ((long)c << 16));
        fa[c] = f2.x; fb[c] = f2.y;
    }
    const float2 m = *reinterpret_cast<const float2*>(ap + ((long)7 << 16));

    // layer 1: 7 -> 16 (112 weights, one chunk)
    float h1a[16], h1b[16];
    {
        float aA[16], aB[16];
        #pragma unroll
        for (int i = 0; i < 16; ++i) { aA[i] = b1[i]; aB[i] = aA[i]; }
        #pragma unroll
        for (int k = 0; k < 7; ++k) {
            #pragma unroll
            for (int i = 0; i < 16; ++i) {
                const float wv = w1[i * 7 + k];        // uniform
                aA[i] += wv * fa[k];
                aB[i] += wv * fb[k];
            }
        }
        #pragma unroll
        for (int i = 0; i < 16; ++i) {
            h1a[i] = fmaxf(aA[i], 0.f);
            h1b[i] = fmaxf(aB[i], 0.f);
        }
    }

    // layer 2: 16 -> 32, o-chunks of 8 (128-weight live window)
    float h2a[32], h2b[32];
    for (int o0 = 0; o0 < 32; o0 += 8) {
        float aA[8], aB[8];
        #pragma unroll
        for (int i = 0; i < 8; ++i) { aA[i] = b2[o0 + i]; aB[i] = aA[i]; }
        #pragma unroll
        for (int k = 0; k < 16; ++k) {
            #pragma unroll
            for (int i = 0; i < 8; ++i) {
                const float wv = w2[(o0 + i) * 16 + k];  // uniform
                aA[i] += wv * h1a[k];
                aB[i] += wv * h1b[k];
            }
        }
        #pragma unroll
        for (int i = 0; i < 8; ++i) {
            h2a[o0 + i] = fmaxf(aA[i], 0.f);
            h2b[o0 + i] = fmaxf(aB[i], 0.f);
        }
    }

    // layer 3: 32 -> 64, o-chunks of 16, k unroll 8 (128-weight live window)
    float* op = Aw + ((long)n * COUT << 16) + rem;
    for (int o0 = 0; o0 < 64; o0 += 16) {
        float aA[16], aB[16];
        #pragma unroll
        for (int i = 0; i < 16; ++i) { aA[i] = b3[o0 + i]; aB[i] = aA[i]; }
        #pragma unroll 8
        for (int k = 0; k < 32; ++k) {
            #pragma unroll
            for (int i = 0; i < 16; ++i) {
                const float wv = w3[(o0 + i) * 32 + k];  // uniform
                aA[i] += wv * h2a[k];
                aB[i] += wv * h2b[k];
            }
        }
        #pragma unroll
        for (int i = 0; i < 16; ++i) {
            float2 r;
            r.x = fmaxf(aA[i], 0.f) * m.x;
            r.y = fmaxf(aB[i], 0.f) * m.y;
            *reinterpret_cast<float2*>(op + ((long)(o0 + i) << 16)) = r;
        }
    }
}

// ---------------------------------------------------------------------------
// K3: out[n,c,t,w] = sum_v y[n,c,t,v] * Aw[n,c,v,w]
// block = (n, c-quad): 1024 blocks, 256 threads = 4 c-lanes x 64 w-lanes,
// thread owns 4 w (float4 Aw loads). y tiles (48 KB) staged in LDS.
// Inner loop over v in groups of 4: 12 INDEPENDENT broadcast ds_read_b128
// (x' for all t) + 4 coalesced 16B Aw loads feed 192 FMAs -> DS pipe off
// the critical path; kernel is Aw-stream (HBM) bound. In-place safe.
// ---------------------------------------------------------------------------
__global__ __launch_bounds__(256) void k3_einsum(
    const float* __restrict__ Aw, const float* __restrict__ y,
    float* __restrict__ out)
{
    __shared__ float ys[4][TT][VV];     // 48 KiB

    const int n   = blockIdx.x >> 4;
    const int c0  = (blockIdx.x & 15) * 4;
    const int tid = threadIdx.x;
    const int cq  = tid >> 6;           // 0..3 (wave-uniform)
    const int w4  = (tid & 63) * 4;     // 0..252

    // stage 4 y tiles: 3072 float4s, 12 per thread, coalesced
    {
        const float* src = y + ((long)(n * COUT + c0) * TT) * VV;
        float* dst = &ys[0][0][0];
        #pragma unroll
        for (int it = 0; it < 12; ++it) {
            const int idx = tid + it * 256;
            *reinterpret_cast<float4*>(dst + idx * 4) =
                *reinterpret_cast<const float4*>(src + idx * 4);
        }
    }
    __syncthreads();

    const float* awp = Aw + (((long)(n * COUT + c0 + cq)) << 16) + w4;
    float4 acc[TT];
    #pragma unroll
    for (int t = 0; t < TT; ++t) acc[t] = make_float4(0.f, 0.f, 0.f, 0.f);

    for (int v0 = 0; v0 < VV; v0 += 4) {
        // 12 independent broadcast b128 reads (all t for this v-group)
        float4 xs[TT];
        #pragma unroll
        for (int t = 0; t < TT; ++t)
            xs[t] = *reinterpret_cast<const float4*>(&ys[cq][t][v0]);

        // 4 coalesced Aw row-segments (1 KB/wave each)
        const float4 aw0 = *reinterpret_cast<const float4*>(awp + (long)(v0 + 0) * VV);
        const float4 aw1 = *reinterpret_cast<const float4*>(awp + (long)(v0 + 1) * VV);
        const float4 aw2 = *reinterpret_cast<const float4*>(awp + (long)(v0 + 2) * VV);
        const float4 aw3 = *reinterpret_cast<const float4*>(awp + (long)(v0 + 3) * VV);

        #pragma unroll
        for (int t = 0; t < TT; ++t) {
            acc[t].x += xs[t].x * aw0.x + xs[t].y * aw1.x + xs[t].z * aw2.x + xs[t].w * aw3.x;
            acc[t].y += xs[t].x * aw0.y + xs[t].y * aw1.y + xs[t].z * aw2.y + xs[t].w * aw3.y;
            acc[t].z += xs[t].x * aw0.z + xs[t].y * aw1.z + xs[t].z * aw2.z + xs[t].w * aw3.z;
            acc[t].w += xs[t].x * aw0.w + xs[t].y * aw1.w + xs[t].z * aw2.w + xs[t].w * aw3.w;
        }
    }

    float* op = out + ((long)(n * COUT + c0 + cq) * TT) * VV + w4;
    #pragma unroll
    for (int t = 0; t < TT; ++t)
        *reinterpret_cast<float4*>(op + t * VV) = acc[t];
}

// ---------------------------------------------------------------------------
extern "C" void kernel_launch(void* const* d_in, const int* in_sizes, int n_in,
                              void* d_out, int out_size, void* d_ws, size_t ws_size,
                              hipStream_t stream)
{
    const float* x      = (const float*)d_in[0];
    const float* A      = (const float*)d_in[1];
    const float* conv_w = (const float*)d_in[2];
    const float* conv_b = (const float*)d_in[3];
    const float* w1     = (const float*)d_in[4];
    const float* b1     = (const float*)d_in[5];
    const float* w2     = (const float*)d_in[6];
    const float* b2     = (const float*)d_in[7];
    const float* w3     = (const float*)d_in[8];
    const float* b3     = (const float*)d_in[9];

    float* out = (float*)d_out;                                  // (64,64,12,256)
    float* Aw  = (float*)d_out + (long)NB * COUT * TT * VV;      // (64,64,256,256)
    const size_t y_bytes = (size_t)NB * COUT * TT * VV * sizeof(float);

    float* y = (ws_size >= y_bytes) ? (float*)d_ws : out;        // k3 handles alias

    // K1: conv -> y
    k1_conv<<<NB * TT, 256, 0, stream>>>(x, conv_w, conv_b, y);

    // K2: MLP + mask -> Aw
    k2_mlp<<<(NB * VSQ) / 512, 256, 0, stream>>>(A, w1, b1, w2, b2, w3, b3, Aw);

    // K3: einsum (in-place safe if y == out)
    k3_einsum<<<NB * (COUT / 4), 256, 0, stream>>>(Aw, y, out);
}

// Round 7
// 631.180 us; speedup vs baseline: 1.5707x; 1.1316x over previous
//
#include <hip/hip_runtime.h>
#include <hip/hip_bf16.h>

// Problem constants
#define NB   64      // batch N
#define TT   12      // T
#define VV   256     // V (vertices)
#define CIN  64
#define COUT 64
#define VSQ  65536   // V*V

typedef float f32x4 __attribute__((ext_vector_type(4)));  // nontemporal-compatible

// ---------------------------------------------------------------------------
// K1: y[n,o,t,v] = sum_c x[n,c,t,v] * conv_w[o,c] + conv_b[o]
// block = (n*T + t), 256 threads (thread = v). Proven ~20 us (BW floor).
// ---------------------------------------------------------------------------
__global__ __launch_bounds__(256) void k1_conv(
    const float* __restrict__ x, const float* __restrict__ w,
    const float* __restrict__ b, float* __restrict__ y)
{
    const int nt = blockIdx.x;
    const int n  = nt / TT;
    const int t  = nt % TT;
    const int v  = threadIdx.x;

    const float* xp = x + ((long)n * CIN * TT + t) * VV + v;
    float xv[CIN];
    #pragma unroll 8
    for (int c = 0; c < CIN; ++c)
        xv[c] = xp[(long)c * TT * VV];          // coalesced

    float* yp = y + ((long)n * COUT * TT + t) * VV + v;

    for (int o0 = 0; o0 < COUT; o0 += 16) {
        float acc[16];
        #pragma unroll
        for (int i = 0; i < 16; ++i) acc[i] = b[o0 + i];
        #pragma unroll 8
        for (int c = 0; c < CIN; ++c) {
            const float xc = xv[c];
            #pragma unroll
            for (int i = 0; i < 16; ++i)
                acc[i] += w[(o0 + i) * CIN + c] * xc;   // uniform -> s_load
        }
        #pragma unroll
        for (int i = 0; i < 16; ++i)
            yp[(long)(o0 + i) * TT * VV] = acc[i];
    }
}

// ---------------------------------------------------------------------------
// K2: Aw[n,c,v,w] = relu(W3 relu(W2 relu(W1 feats + b1) + b2) + b3) * mask
// OCCUPANCY-FIRST variant: 1 position/thread, o-chunks of 8 with immediate
// rolling nontemporal stores. Live state ~75-85 VGPR; __launch_bounds__
// (256,5) pins >=5 waves/SIMD so store/load latency overlaps across waves.
// Weights stay wave-uniform global (s_load + K$, scalar pipe).
// ---------------------------------------------------------------------------
__global__ __launch_bounds__(256, 5) void k2_mlp(
    const float* __restrict__ A,
    const float* __restrict__ w1, const float* __restrict__ b1,
    const float* __restrict__ w2, const float* __restrict__ b2,
    const float* __restrict__ w3, const float* __restrict__ b3,
    float* __restrict__ Aw)
{
    const long idx = (long)blockIdx.x * 256 + threadIdx.x;  // n*VSQ + pos
    const int  n   = (int)(idx >> 16);
    const int  rem = (int)(idx & (VSQ - 1));

    const float* ap = A + ((long)n * 8 << 16) + rem;
    float f[7];
    #pragma unroll
    for (int c = 0; c < 7; ++c) f[c] = ap[(long)c << 16];
    const float m = ap[(long)7 << 16];

    // layer 1: 7 -> 16
    float h1[16];
    #pragma unroll
    for (int o = 0; o < 16; ++o) {
        float acc = b1[o];
        #pragma unroll
        for (int k = 0; k < 7; ++k) acc += w1[o * 7 + k] * f[k];   // uniform
        h1[o] = fmaxf(acc, 0.f);
    }

    // layer 2: 16 -> 32
    float h2[32];
    #pragma unroll
    for (int o = 0; o < 32; ++o) {
        float acc = b2[o];
        #pragma unroll
        for (int k = 0; k < 16; ++k) acc += w2[o * 16 + k] * h1[k]; // uniform
        h2[o] = fmaxf(acc, 0.f);
    }

    // layer 3: 32 -> 64 in o-chunks of 8; store each chunk immediately
    float* op = Aw + ((long)n * COUT << 16) + rem;
    for (int o0 = 0; o0 < 64; o0 += 8) {
        float acc[8];
        #pragma unroll
        for (int i = 0; i < 8; ++i) acc[i] = b3[o0 + i];
        #pragma unroll
        for (int k = 0; k < 32; ++k) {
            #pragma unroll
            for (int i = 0; i < 8; ++i)
                acc[i] += w3[(o0 + i) * 32 + k] * h2[k];            // uniform
        }
        #pragma unroll
        for (int i = 0; i < 8; ++i)
            __builtin_nontemporal_store(fmaxf(acc[i], 0.f) * m,
                                        op + ((long)(o0 + i) << 16));
    }
}

// ---------------------------------------------------------------------------
// K3: out[n,c,t,w] = sum_v y[n,c,t,v] * Aw[n,c,v,w]
// Proven R5 structure: block = (n, c-quad), 48 KB LDS y tiles, per v-group-4:
// 12 broadcast ds_read_b128 + 4 coalesced 16B nt Aw loads -> 192 FMAs.
// In-place safe (reads of y complete before barrier; writes after).
// ---------------------------------------------------------------------------
__global__ __launch_bounds__(256) void k3_einsum(
    const float* __restrict__ Aw, const float* __restrict__ y,
    float* __restrict__ out)
{
    __shared__ float ys[4][TT][VV];     // 48 KiB

    const int n   = blockIdx.x >> 4;
    const int c0  = (blockIdx.x & 15) * 4;
    const int tid = threadIdx.x;
    const int cq  = tid >> 6;           // 0..3 (wave-uniform)
    const int w4  = (tid & 63) * 4;     // 0..252

    // stage 4 y tiles: 3072 float4s, 12 per thread, coalesced
    {
        const float* src = y + ((long)(n * COUT + c0) * TT) * VV;
        float* dst = &ys[0][0][0];
        #pragma unroll
        for (int it = 0; it < 12; ++it) {
            const int idx = tid + it * 256;
            *reinterpret_cast<float4*>(dst + idx * 4) =
                *reinterpret_cast<const float4*>(src + idx * 4);
        }
    }
    __syncthreads();

    const float* awp = Aw + (((long)(n * COUT + c0 + cq)) << 16) + w4;
    float4 acc[TT];
    #pragma unroll
    for (int t = 0; t < TT; ++t) acc[t] = make_float4(0.f, 0.f, 0.f, 0.f);

    for (int v0 = 0; v0 < VV; v0 += 4) {
        // 12 independent broadcast b128 reads (all t for this v-group)
        float4 xs[TT];
        #pragma unroll
        for (int t = 0; t < TT; ++t)
            xs[t] = *reinterpret_cast<const float4*>(&ys[cq][t][v0]);

        // 4 coalesced nontemporal Aw row-segments (single-use stream)
        const f32x4 aw0 = __builtin_nontemporal_load(
            reinterpret_cast<const f32x4*>(awp + (long)(v0 + 0) * VV));
        const f32x4 aw1 = __builtin_nontemporal_load(
            reinterpret_cast<const f32x4*>(awp + (long)(v0 + 1) * VV));
        const f32x4 aw2 = __builtin_nontemporal_load(
            reinterpret_cast<const f32x4*>(awp + (long)(v0 + 2) * VV));
        const f32x4 aw3 = __builtin_nontemporal_load(
            reinterpret_cast<const f32x4*>(awp + (long)(v0 + 3) * VV));

        #pragma unroll
        for (int t = 0; t < TT; ++t) {
            acc[t].x += xs[t].x * aw0.x + xs[t].y * aw1.x + xs[t].z * aw2.x + xs[t].w * aw3.x;
            acc[t].y += xs[t].x * aw0.y + xs[t].y * aw1.y + xs[t].z * aw2.y + xs[t].w * aw3.y;
            acc[t].z += xs[t].x * aw0.z + xs[t].y * aw1.z + xs[t].z * aw2.z + xs[t].w * aw3.z;
            acc[t].w += xs[t].x * aw0.w + xs[t].y * aw1.w + xs[t].z * aw2.w + xs[t].w * aw3.w;
        }
    }

    float* op = out + ((long)(n * COUT + c0 + cq) * TT) * VV + w4;
    #pragma unroll
    for (int t = 0; t < TT; ++t)
        *reinterpret_cast<float4*>(op + t * VV) = acc[t];
}

// ---------------------------------------------------------------------------
extern "C" void kernel_launch(void* const* d_in, const int* in_sizes, int n_in,
                              void* d_out, int out_size, void* d_ws, size_t ws_size,
                              hipStream_t stream)
{
    const float* x      = (const float*)d_in[0];
    const float* A      = (const float*)d_in[1];
    const float* conv_w = (const float*)d_in[2];
    const float* conv_b = (const float*)d_in[3];
    const float* w1     = (const float*)d_in[4];
    const float* b1     = (const float*)d_in[5];
    const float* w2     = (const float*)d_in[6];
    const float* b2     = (const float*)d_in[7];
    const float* w3     = (const float*)d_in[8];
    const float* b3     = (const float*)d_in[9];

    float* out = (float*)d_out;                                  // (64,64,12,256)
    float* Aw  = (float*)d_out + (long)NB * COUT * TT * VV;      // (64,64,256,256)
    const size_t y_bytes = (size_t)NB * COUT * TT * VV * sizeof(float);

    float* y = (ws_size >= y_bytes) ? (float*)d_ws : out;        // k3 handles alias

    // K1: conv -> y
    k1_conv<<<NB * TT, 256, 0, stream>>>(x, conv_w, conv_b, y);

    // K2: MLP + mask -> Aw (occupancy-first variant)
    k2_mlp<<<(NB * VSQ) / 256, 256, 0, stream>>>(A, w1, b1, w2, b2, w3, b3, Aw);

    // K3: einsum (in-place safe if y == out)
    k3_einsum<<<NB * (COUT / 4), 256, 0, stream>>>(Aw, y, out);
}